// Round 11
// baseline (528.904 us; speedup 1.0000x reference)
//
#include <hip/hip_runtime.h>

#define BB 128
#define LL 256
#define DD 384
#define QB 64

typedef __attribute__((ext_vector_type(8))) _Float16 half8;
typedef __attribute__((ext_vector_type(4))) _Float16 half4;
typedef __attribute__((ext_vector_type(4))) float f32x4;
typedef __attribute__((ext_vector_type(4))) uint  u32x4;

union fragh { u32x4 u; half8 h; };

__device__ inline uint packrtz(float a, float b) {
  auto h = __builtin_amdgcn_cvt_pkrtz(a, b);
  return __builtin_bit_cast(uint, h);
}

__device__ inline half4 cvt4(f32x4 a) {
  uint2 u = make_uint2(packrtz(a[0], a[1]), packrtz(a[2], a[3]));
  return __builtin_bit_cast(half4, u);
}

__device__ inline half8 ld_frag8h(const short* p) {
  uint2 lo = *(const uint2*)p;
  uint2 hi = *(const uint2*)(p + 4);
  fragh f;
  f.u[0] = lo.x; f.u[1] = lo.y; f.u[2] = hi.x; f.u[3] = hi.y;
  return f.h;
}

#define MFMA16 __builtin_amdgcn_mfma_f32_16x16x32_f16
#define MFMA16K16 __builtin_amdgcn_mfma_f32_16x16x16f16

typedef const __attribute__((address_space(1))) uint ga_uint;
typedef __attribute__((address_space(3))) uint ls_uint;

// MODE 0: full real pipeline (writes accum).
// MODE 1: Phase A only, x4 reps, rep-chained (writes scratch).
// MODE 2: softmax+P+PV+epilogue only, x2 reps, junk scores (writes scratch).
template<int MODE>
__global__ __launch_bounds__(512, 4) void abl_kernel(
    const float* __restrict__ qf, const float* __restrict__ af,
    const int* __restrict__ qm, const int* __restrict__ am,
    float* __restrict__ accum, float* __restrict__ scratch)
{
  const int bid = blockIdx.x;
  const int blo = bid & 7, r1 = bid >> 3;
  const int tl = r1 & 7, bhi = r1 >> 3;
  const int b = bhi * 8 + blo;
  const int side = tl >> 2, r0 = (tl & 3) * QB;

  const float* self = side ? af : qf;
  const float* feat = side ? qf : af;
  const int*   msk  = side ? am : qm;

  __shared__ __align__(16) float sFeat[2][LL * 16];
  __shared__ __align__(16) float sSelf[2][QB * 16];
  __shared__ __align__(16) short sVtb[DD * 36];
  __shared__ float sRedM[8][QB];
  __shared__ float sRedS[8][QB];
  __shared__ float sInv[QB];
  __shared__ float sSsq[QB];
  __shared__ float sPool[DD];

  short (*sVt)[36] = (short(*)[36])sVtb;
  short* sAl = (short*)sFeat;

  const int t = threadIdx.x;
  const int w = t >> 6, lane = t & 63;
  const int lam = lane & 15, g = lane >> 4;

  const float* selfb = self + ((size_t)b * LL + r0) * DD;
  const float* featb = feat + (size_t)b * LL * DD;

  const int lg16 = ((lane & 3) ^ ((lane >> 3) & 3)) * 4;
  const int lrow = lane >> 2;
  const int key  = (lam >> 1) & 3;

  #define STAGE16(kc_, bi_) do {                                                  \
    const int k0_ = (kc_) * 16;                                                   \
    _Pragma("unroll")                                                             \
    for (int i = 0; i < 2; ++i) {                                                 \
      int R = w * 32 + i * 16;                                                    \
      __builtin_amdgcn_global_load_lds(                                           \
          (ga_uint*)&featb[(size_t)(R + lrow) * DD + k0_ + lg16],                 \
          (ls_uint*)&sFeat[bi_][R * 16], 16, 0, 0);                               \
    }                                                                             \
    if (w < 4) {                                                                  \
      int R = w * 16;                                                             \
      __builtin_amdgcn_global_load_lds(                                           \
          (ga_uint*)&selfb[(size_t)(R + lrow) * DD + k0_ + lg16],                 \
          (ls_uint*)&sSelf[bi_][R * 16], 16, 0, 0);                               \
    }                                                                             \
  } while (0)

  // PV staging precompute (used by MODE 0/2)
  int   di[6], tgi[6];
  short* wp[6];
  #pragma unroll
  for (int i = 0; i < 6; ++i) {
    int u = t + i * 512;
    int tg = u / 384, d = u - tg * 384;
    di[i] = d; tgi[i] = tg;
    int sw = (d & 1) | (((d >> 4) & 1) << 1);
    wp[i] = &sVt[d][(((tg >> 1) ^ sw) << 3) + ((tg & 1) << 2)];
  }

  float v0[6], v1[6], v2[6], v3[6];
  #define LOADV(ac_) do {                                                          \
    const int k0_ = (ac_) * 32;                                                    \
    _Pragma("unroll")                                                              \
    for (int i = 0; i < 6; ++i) {                                                  \
      const float* fp = &featb[(size_t)(k0_ + tgi[i] * 4) * DD + di[i]];           \
      v0[i] = fp[0];                                                               \
      v1[i] = fp[DD];                                                              \
      v2[i] = fp[2 * DD];                                                          \
      v3[i] = fp[3 * DD];                                                          \
    }                                                                              \
  } while (0)

  constexpr int REPS = (MODE == 1) ? 4 : (MODE == 2) ? 2 : 1;
  float carry = 0.f;

  f32x4 accS[4][2];
  f32x4 accP[4][3];

  for (int rep = 0; rep < REPS; ++rep) {
    if constexpr (MODE != 2) {
      // ---------------- Phase A ----------------
      #pragma unroll
      for (int rt = 0; rt < 4; ++rt)
        #pragma unroll
        for (int ct = 0; ct < 2; ++ct)
          #pragma unroll
          for (int rg = 0; rg < 4; ++rg)
            accS[rt][ct][rg] = (MODE == 0) ? 0.f : carry;
      STAGE16(0, 0);
      __syncthreads();
      for (int kc = 0; kc < 24; ++kc) {
        const int cur = kc & 1;
        if (kc < 23) STAGE16(kc + 1, cur ^ 1);
        half4 ah[4], bh[2];
        #pragma unroll
        for (int rt = 0; rt < 4; ++rt)
          ah[rt] = cvt4(*(const f32x4*)&sSelf[cur][(rt * 16 + lam) * 16 + ((g ^ key) << 2)]);
        #pragma unroll
        for (int ct = 0; ct < 2; ++ct)
          bh[ct] = cvt4(*(const f32x4*)&sFeat[cur][(w * 32 + ct * 16 + lam) * 16 + ((g ^ key) << 2)]);
        __builtin_amdgcn_s_setprio(1);
        #pragma unroll
        for (int rt = 0; rt < 4; ++rt)
          #pragma unroll
          for (int ct = 0; ct < 2; ++ct)
            accS[rt][ct] = MFMA16K16(ah[rt], bh[ct], accS[rt][ct], 0, 0, 0);
        __builtin_amdgcn_s_setprio(0);
        __syncthreads();
      }
      if constexpr (MODE == 1) {
        carry = 1e-30f * (accS[0][0][0] + accS[3][1][3] + accS[1][0][2]);
        continue;
      }
    } else {
      // junk scores with spread (rep-chained so reps don't collapse)
      __syncthreads();
      #pragma unroll
      for (int rt = 0; rt < 4; ++rt)
        #pragma unroll
        for (int ct = 0; ct < 2; ++ct)
          #pragma unroll
          for (int rg = 0; rg < 4; ++rg)
            accS[rt][ct][rg] = carry + 0.1f * (float)((lane * 7 + rt * 3 + ct * 5 + rg) & 15);
    }

    // ---------------- Softmax ----------------
    #pragma unroll
    for (int rt = 0; rt < 4; ++rt)
      #pragma unroll
      for (int rg = 0; rg < 4; ++rg) {
        float m = fmaxf(accS[rt][0][rg], accS[rt][1][rg]);
        #pragma unroll
        for (int off = 1; off < 16; off <<= 1) m = fmaxf(m, __shfl_xor(m, off));
        if (lam == 0) sRedM[w][rt * 16 + g * 4 + rg] = m;
      }
    __syncthreads();
    #pragma unroll
    for (int rt = 0; rt < 4; ++rt)
      #pragma unroll
      for (int rg = 0; rg < 4; ++rg) {
        int row = rt * 16 + g * 4 + rg;
        float m = sRedM[0][row];
        #pragma unroll
        for (int ww = 1; ww < 8; ++ww) m = fmaxf(m, sRedM[ww][row]);
        float s = 0.f;
        #pragma unroll
        for (int ct = 0; ct < 2; ++ct) {
          float p = __expf(accS[rt][ct][rg] - m);
          accS[rt][ct][rg] = p;
          s += p;
        }
        #pragma unroll
        for (int off = 1; off < 16; off <<= 1) s += __shfl_xor(s, off);
        if (lam == 0) sRedS[w][row] = s;
      }
    __syncthreads();
    #pragma unroll
    for (int rt = 0; rt < 4; ++rt)
      #pragma unroll
      for (int rg = 0; rg < 4; ++rg) {
        int row = rt * 16 + g * 4 + rg;
        float s = 0.f;
        #pragma unroll
        for (int ww = 0; ww < 8; ++ww) s += sRedS[ww][row];
        float inv = 1.f / s;
        #pragma unroll
        for (int ct = 0; ct < 2; ++ct) {
          int c = w * 32 + ct * 16 + lam;
          _Float16 ph = (_Float16)(accS[rt][ct][rg] * inv);
          sAl[((c >> 3) * QB + row) * 8 + (c & 7)] =
              (short)__builtin_bit_cast(unsigned short, ph);
        }
      }
    __syncthreads();

    // ---------------- PV ----------------
    #pragma unroll
    for (int rt = 0; rt < 4; ++rt)
      #pragma unroll
      for (int dt = 0; dt < 3; ++dt)
        #pragma unroll
        for (int rg = 0; rg < 4; ++rg)
          accP[rt][dt][rg] = 0.f;
    LOADV(0);
    for (int ac = 0; ac < 8; ++ac) {
      #pragma unroll
      for (int i = 0; i < 6; ++i)
        *(uint2*)wp[i] = make_uint2(packrtz(v0[i], v1[i]), packrtz(v2[i], v3[i]));
      __syncthreads();
      if (ac < 7) LOADV(ac + 1);
      fragh pf[4];
      half8 vf[3];
      #pragma unroll
      for (int rt = 0; rt < 4; ++rt)
        pf[rt].u = *(const u32x4*)&sAl[((ac * 4 + g) * QB + rt * 16 + lam) * 8];
      #pragma unroll
      for (int dt = 0; dt < 3; ++dt) {
        int swr = (lam & 1) | (((w * 3 + dt) & 1) << 1);
        vf[dt] = ld_frag8h(&sVt[w * 48 + dt * 16 + lam][(g ^ swr) * 8]);
      }
      __builtin_amdgcn_s_setprio(1);
      #pragma unroll
      for (int rt = 0; rt < 4; ++rt)
        #pragma unroll
        for (int dt = 0; dt < 3; ++dt)
          accP[rt][dt] = MFMA16(pf[rt].h, vf[dt], accP[rt][dt], 0, 0, 0);
      __builtin_amdgcn_s_setprio(0);
      __syncthreads();
    }

    // ---------------- Epilogue ----------------
    #pragma unroll
    for (int rt = 0; rt < 4; ++rt)
      #pragma unroll
      for (int rg = 0; rg < 4; ++rg) {
        float s = 0.f;
        #pragma unroll
        for (int dt = 0; dt < 3; ++dt) s += accP[rt][dt][rg] * accP[rt][dt][rg];
        #pragma unroll
        for (int off = 1; off < 16; off <<= 1) s += __shfl_xor(s, off);
        if (lam == 0) sRedM[w][rt * 16 + g * 4 + rg] = s;
      }
    {
      int sr = t >> 3, sc = (t & 7) * 4;
      const float* sp = &selfb[(size_t)sr * DD];
      float ss = 0.f;
      #pragma unroll
      for (int j = 0; j < 12; ++j) {
        float4 v = *(const float4*)&sp[sc + j * 32];
        ss += v.x * v.x + v.y * v.y + v.z * v.z + v.w * v.w;
      }
      ss += __shfl_xor(ss, 1); ss += __shfl_xor(ss, 2); ss += __shfl_xor(ss, 4);
      if ((t & 7) == 0) sSsq[sr] = ss;
    }
    __syncthreads();
    if (t < QB) {
      float tot = sSsq[t];
      #pragma unroll
      for (int ww = 0; ww < 8; ++ww) tot += sRedM[ww][t];
      int mv = msk[(size_t)b * LL + r0 + t];
      sInv[t] = mv ? (1.f / fmaxf(sqrtf(tot), 1e-12f)) : 0.f;
    }
    __syncthreads();
    #pragma unroll
    for (int dt = 0; dt < 3; ++dt) {
      float pa = 0.f;
      #pragma unroll
      for (int rt = 0; rt < 4; ++rt)
        #pragma unroll
        for (int rg = 0; rg < 4; ++rg)
          pa += sInv[rt * 16 + g * 4 + rg] * accP[rt][dt][rg];
      pa += __shfl_xor(pa, 16);
      pa += __shfl_xor(pa, 32);
      if (g == 0) sPool[w * 48 + dt * 16 + lam] = pa;
    }
    __syncthreads();
    if (t < DD) {
      float* ac = ((MODE == 0) ? accum : scratch) + ((size_t)side * BB + b) * 2 * DD;
      float ps = 0.f;
      const float* sp = selfb + t;
      #pragma unroll 4
      for (int r = 0; r < QB; ++r) ps = fmaf(sInv[r], sp[(size_t)r * DD], ps);
      atomicAdd(&ac[t], ps);
      atomicAdd(&ac[DD + t], sPool[t]);
    }
    if constexpr (MODE == 2) {
      carry = 1e-30f * (accP[0][0][0] + accP[3][2][3]);
      __syncthreads();
    }
  }

  if constexpr (MODE != 0)
    scratch[(size_t)(2 * BB * 2 * DD) + (size_t)bid * 512 + t] = carry;
}

// ---------------- Finalize: divide by mask count, final l2norm ----------------
__global__ __launch_bounds__(256) void finalize_kernel(
    const float* __restrict__ accum, const int* __restrict__ qm,
    const int* __restrict__ am, float* __restrict__ out)
{
  const int b    = blockIdx.x & (BB - 1);
  const int side = blockIdx.x >> 7;
  const int* msk = side ? am : qm;
  const int t = threadIdx.x;
  __shared__ float red[8];

  float c = (float)msk[(size_t)b * LL + t];
  #pragma unroll
  for (int off = 1; off < 64; off <<= 1) c += __shfl_xor(c, off);
  if ((t & 63) == 0) red[t >> 6] = c;
  __syncthreads();
  float cnt = fmaxf(red[0] + red[1] + red[2] + red[3], 1e-9f);

  const float* ac = accum + ((size_t)side * BB + b) * 2 * DD;
  float v[3];
  float ssq = 0.f;
  #pragma unroll
  for (int i = 0; i < 3; ++i) {
    v[i] = ac[t * 3 + i] / cnt;
    ssq += v[i] * v[i];
  }
  #pragma unroll
  for (int off = 1; off < 64; off <<= 1) ssq += __shfl_xor(ssq, off);
  __syncthreads();
  if ((t & 63) == 0) red[t >> 6] = ssq;
  __syncthreads();
  float n = sqrtf(red[0] + red[1] + red[2] + red[3]);
  float inv = 1.f / fmaxf(n, 1e-12f);
  float* ob = out + ((size_t)side * BB + b) * 2 * DD;
  #pragma unroll
  for (int i = 0; i < 3; ++i) ob[t * 3 + i] = v[i] * inv;
}

extern "C" void kernel_launch(void* const* d_in, const int* in_sizes, int n_in,
                              void* d_out, int out_size, void* d_ws, size_t ws_size,
                              hipStream_t stream) {
  const float* qf = (const float*)d_in[0];
  const float* af = (const float*)d_in[1];
  const int*   qm = (const int*)d_in[2];
  const int*   am = (const int*)d_in[3];
  float* out   = (float*)d_out;
  float* accum = (float*)d_ws;                                  // 786 KB
  const size_t ablsz = (size_t)2 * BB * 2 * DD + (size_t)1024 * 512;
  float* scr1  = accum + (size_t)2 * BB * 2 * DD;               // ablation scratch 1
  float* scr2  = scr1 + ablsz;                                  // ablation scratch 2

  (void)hipMemsetAsync(accum, 0, sizeof(float) * 2 * BB * 2 * DD, stream);
  abl_kernel<0><<<dim3(1024), 512, 0, stream>>>(qf, af, qm, am, accum, scr1);
  finalize_kernel<<<256, 256, 0, stream>>>(accum, qm, am, out);
  abl_kernel<1><<<dim3(1024), 512, 0, stream>>>(qf, af, qm, am, accum, scr1);
  abl_kernel<2><<<dim3(1024), 512, 0, stream>>>(qf, af, qm, am, accum, scr2);
}

// Round 12
// 115.929 us; speedup vs baseline: 4.5623x; 4.5623x over previous
//
#include <hip/hip_runtime.h>

#define BB 128
#define LL 256
#define DD 384
#define QB 64

typedef __attribute__((ext_vector_type(8))) _Float16 half8;
typedef __attribute__((ext_vector_type(4))) _Float16 half4;
typedef __attribute__((ext_vector_type(4))) float f32x4;
typedef __attribute__((ext_vector_type(4))) uint  u32x4;

union fragh { u32x4 u; half8 h; };

__device__ inline uint packrtz(float a, float b) {
  auto h = __builtin_amdgcn_cvt_pkrtz(a, b);
  return __builtin_bit_cast(uint, h);
}

__device__ inline half4 cvt4(f32x4 a) {
  uint2 u = make_uint2(packrtz(a[0], a[1]), packrtz(a[2], a[3]));
  return __builtin_bit_cast(half4, u);
}

__device__ inline half8 ld_frag8h(const short* p) {
  uint2 lo = *(const uint2*)p;
  uint2 hi = *(const uint2*)(p + 4);
  fragh f;
  f.u[0] = lo.x; f.u[1] = lo.y; f.u[2] = hi.x; f.u[3] = hi.y;
  return f.h;
}

#define MFMA16 __builtin_amdgcn_mfma_f32_16x16x32_f16
#define MFMA16K16 __builtin_amdgcn_mfma_f32_16x16x16f16

typedef const __attribute__((address_space(1))) uint ga_uint;
typedef __attribute__((address_space(3))) uint ls_uint;

// One block per (batch, side, 64-row tile). 512 threads = 8 waves, wave-grid 1x8.
__global__ __launch_bounds__(512, 4) void fused_kernel(
    const float* __restrict__ qf, const float* __restrict__ af,
    const int* __restrict__ qm, const int* __restrict__ am,
    float* __restrict__ accum)
{
  // XCD-affine decode: xcd = bid&7 = b&7 -> all 8 tiles of a batch on one XCD
  const int bid = blockIdx.x;
  const int blo = bid & 7, r1 = bid >> 3;
  const int tl = r1 & 7, bhi = r1 >> 3;
  const int b = bhi * 8 + blo;
  const int side = tl >> 2, r0 = (tl & 3) * QB;

  const float* self = side ? af : qf;   // rows we attend FROM
  const float* feat = side ? qf : af;   // rows we attend TO
  const int*   msk  = side ? am : qm;

  // 61440B staging union:
  //   Phase A: feat bufs [0,49152) = 3 x 16KB, self bufs [49152,61440) = 3 x 4KB
  //   After A: sAl (P fp16) = bytes [0,32768); sVt (featT) = bytes [32768,60416)
  __shared__ __align__(16) float sU[15360];
  __shared__ float sRedM[8][QB];
  __shared__ float sRedS[8][QB];
  __shared__ float sInv[QB];
  __shared__ float sSsq[QB];
  __shared__ float sPool[DD];

  short* sAl = (short*)sU;
  short (*sVt)[36] = (short(*)[36])((char*)sU + 32768);

  const int t = threadIdx.x;
  const int w = t >> 6, lane = t & 63;
  const int lam = lane & 15, g = lane >> 4;

  const float* selfb = self + ((size_t)b * LL + r0) * DD;
  const float* featb = feat + (size_t)b * LL * DD;

  // ---------------- Phase A: counted-vmcnt 3-buffer pipeline (T3+T4 minimum) ----------------
  // gll dest linear; source granule pre-swizzled: lane l supplies logical granule
  // (l&3)^((l>>3)&3) of row base+(l>>2). Read: logical g lives at phys g^((lam>>1)&3).
  const int lg16 = ((lane & 3) ^ ((lane >> 3) & 3)) * 4;   // source col offset (floats)
  const int lrow = lane >> 2;                              // row within 16-row group
  const int key  = (lam >> 1) & 3;                         // read-side XOR key

  // waves 0-3 issue 3 gll/chunk, waves 4-7 issue 2.
  #define STAGE16(kc_, bi_) do {                                                  \
    const int k0_ = (kc_) * 16;                                                   \
    _Pragma("unroll")                                                             \
    for (int i = 0; i < 2; ++i) {                                                 \
      int R = w * 32 + i * 16;                                                    \
      __builtin_amdgcn_global_load_lds(                                           \
          (ga_uint*)&featb[(size_t)(R + lrow) * DD + k0_ + lg16],                 \
          (ls_uint*)&sU[(bi_) * 4096 + R * 16], 16, 0, 0);                        \
    }                                                                             \
    if (w < 4) {                                                                  \
      int R = w * 16;                                                             \
      __builtin_amdgcn_global_load_lds(                                           \
          (ga_uint*)&selfb[(size_t)(R + lrow) * DD + k0_ + lg16],                 \
          (ls_uint*)&sU[12288 + (bi_) * 1024 + R * 16], 16, 0, 0);                \
    }                                                                             \
  } while (0)

  f32x4 accS[4][2] = {};
  STAGE16(0, 0);
  STAGE16(1, 1);
  #pragma unroll
  for (int kc = 0; kc < 24; ++kc) {
    // wait: own chunk-kc loads done (leave chunk kc+1's in flight)
    if (kc < 23) {
      if (w < 4) asm volatile("s_waitcnt vmcnt(3)" ::: "memory");
      else       asm volatile("s_waitcnt vmcnt(2)" ::: "memory");
    } else {
      asm volatile("s_waitcnt vmcnt(0)" ::: "memory");
    }
    __builtin_amdgcn_s_barrier();          // all waves' chunk-kc data visible
    __builtin_amdgcn_sched_barrier(0);
    if (kc < 22) STAGE16(kc + 2, (kc + 2) % 3);   // prefetch 2 ahead
    const int cur = kc % 3;
    half4 ah[4], bh[2];
    #pragma unroll
    for (int rt = 0; rt < 4; ++rt)
      ah[rt] = cvt4(*(const f32x4*)&sU[12288 + cur * 1024 + (rt * 16 + lam) * 16 + ((g ^ key) << 2)]);
    #pragma unroll
    for (int ct = 0; ct < 2; ++ct)
      bh[ct] = cvt4(*(const f32x4*)&sU[cur * 4096 + (w * 32 + ct * 16 + lam) * 16 + ((g ^ key) << 2)]);
    __builtin_amdgcn_s_setprio(1);
    #pragma unroll
    for (int rt = 0; rt < 4; ++rt)
      #pragma unroll
      for (int ct = 0; ct < 2; ++ct)
        accS[rt][ct] = MFMA16K16(ah[rt], bh[ct], accS[rt][ct], 0, 0, 0);
    __builtin_amdgcn_s_setprio(0);
  }

  // ---------------- Softmax over cols (C layout: col=lane&15, row=g*4+rg) ----------------
  #pragma unroll
  for (int rt = 0; rt < 4; ++rt)
    #pragma unroll
    for (int rg = 0; rg < 4; ++rg) {
      float m = fmaxf(accS[rt][0][rg], accS[rt][1][rg]);
      #pragma unroll
      for (int off = 1; off < 16; off <<= 1) m = fmaxf(m, __shfl_xor(m, off));
      if (lam == 0) sRedM[w][rt * 16 + g * 4 + rg] = m;
    }
  __syncthreads();
  #pragma unroll
  for (int rt = 0; rt < 4; ++rt)
    #pragma unroll
    for (int rg = 0; rg < 4; ++rg) {
      int row = rt * 16 + g * 4 + rg;
      float m = sRedM[0][row];
      #pragma unroll
      for (int ww = 1; ww < 8; ++ww) m = fmaxf(m, sRedM[ww][row]);
      float s = 0.f;
      #pragma unroll
      for (int ct = 0; ct < 2; ++ct) {
        float p = __expf(accS[rt][ct][rg] - m);
        accS[rt][ct][rg] = p;
        s += p;
      }
      #pragma unroll
      for (int off = 1; off < 16; off <<= 1) s += __shfl_xor(s, off);
      if (lam == 0) sRedS[w][row] = s;
    }
  __syncthreads();
  #pragma unroll
  for (int rt = 0; rt < 4; ++rt)
    #pragma unroll
    for (int rg = 0; rg < 4; ++rg) {
      int row = rt * 16 + g * 4 + rg;
      float s = 0.f;
      #pragma unroll
      for (int ww = 0; ww < 8; ++ww) s += sRedS[ww][row];
      float inv = 1.f / s;
      #pragma unroll
      for (int ct = 0; ct < 2; ++ct) {
        int c = w * 32 + ct * 16 + lam;
        _Float16 ph = (_Float16)(accS[rt][ct][rg] * inv);
        sAl[((c >> 3) * QB + row) * 8 + (c & 7)] =
            (short)__builtin_bit_cast(unsigned short, ph);
      }
    }
  __syncthreads();

  // ---------------- PV: O[64][384] = P @ feat, granule-swizzled featT staging ----------------
  // wave w: d-cols w*48 + dt*16 + lam (dt=0..2)
  // physical granule = logical ^ sw, sw(d) = (d&1) | (((d>>4)&1)<<1)
  int   di[6], tgi[6];
  short* wp[6];
  #pragma unroll
  for (int i = 0; i < 6; ++i) {
    int u = t + i * 512;
    int tg = u / 384, d = u - tg * 384;
    di[i] = d; tgi[i] = tg;
    int sw = (d & 1) | (((d >> 4) & 1) << 1);
    wp[i] = &sVt[d][(((tg >> 1) ^ sw) << 3) + ((tg & 1) << 2)];
  }

  float v0[6], v1[6], v2[6], v3[6];
  #define LOADV(ac_) do {                                                          \
    const int k0_ = (ac_) * 32;                                                    \
    _Pragma("unroll")                                                              \
    for (int i = 0; i < 6; ++i) {                                                  \
      const float* fp = &featb[(size_t)(k0_ + tgi[i] * 4) * DD + di[i]];           \
      v0[i] = fp[0];                                                               \
      v1[i] = fp[DD];                                                              \
      v2[i] = fp[2 * DD];                                                          \
      v3[i] = fp[3 * DD];                                                          \
    }                                                                              \
  } while (0)

  f32x4 accP[4][3] = {};
  LOADV(0);
  for (int ac = 0; ac < 8; ++ac) {
    #pragma unroll
    for (int i = 0; i < 6; ++i)
      *(uint2*)wp[i] = make_uint2(packrtz(v0[i], v1[i]), packrtz(v2[i], v3[i]));
    __syncthreads();
    if (ac < 7) LOADV(ac + 1);
    fragh pf[4];
    half8 vf[3];
    #pragma unroll
    for (int rt = 0; rt < 4; ++rt)
      pf[rt].u = *(const u32x4*)&sAl[((ac * 4 + g) * QB + rt * 16 + lam) * 8];
    #pragma unroll
    for (int dt = 0; dt < 3; ++dt) {
      int swr = (lam & 1) | (((w * 3 + dt) & 1) << 1);
      vf[dt] = ld_frag8h(&sVt[w * 48 + dt * 16 + lam][(g ^ swr) * 8]);
    }
    __builtin_amdgcn_s_setprio(1);
    #pragma unroll
    for (int rt = 0; rt < 4; ++rt)
      #pragma unroll
      for (int dt = 0; dt < 3; ++dt)
        accP[rt][dt] = MFMA16(pf[rt].h, vf[dt], accP[rt][dt], 0, 0, 0);
    __builtin_amdgcn_s_setprio(0);
    __syncthreads();
  }

  // ---------------- Epilogue: row l2norm over [self|attended], masked pool ----------------
  #pragma unroll
  for (int rt = 0; rt < 4; ++rt)
    #pragma unroll
    for (int rg = 0; rg < 4; ++rg) {
      float s = 0.f;
      #pragma unroll
      for (int dt = 0; dt < 3; ++dt) s += accP[rt][dt][rg] * accP[rt][dt][rg];
      #pragma unroll
      for (int off = 1; off < 16; off <<= 1) s += __shfl_xor(s, off);
      if (lam == 0) sRedM[w][rt * 16 + g * 4 + rg] = s;
    }
  {
    int sr = t >> 3, sc = (t & 7) * 4;
    const float* sp = &selfb[(size_t)sr * DD];
    float ss = 0.f;
    #pragma unroll
    for (int j = 0; j < 12; ++j) {
      float4 v = *(const float4*)&sp[sc + j * 32];
      ss += v.x * v.x + v.y * v.y + v.z * v.z + v.w * v.w;
    }
    ss += __shfl_xor(ss, 1); ss += __shfl_xor(ss, 2); ss += __shfl_xor(ss, 4);
    if ((t & 7) == 0) sSsq[sr] = ss;
  }
  __syncthreads();
  if (t < QB) {
    float tot = sSsq[t];
    #pragma unroll
    for (int ww = 0; ww < 8; ++ww) tot += sRedM[ww][t];
    int mv = msk[(size_t)b * LL + r0 + t];
    sInv[t] = mv ? (1.f / fmaxf(sqrtf(tot), 1e-12f)) : 0.f;
  }
  __syncthreads();
  #pragma unroll
  for (int dt = 0; dt < 3; ++dt) {
    float pa = 0.f;
    #pragma unroll
    for (int rt = 0; rt < 4; ++rt)
      #pragma unroll
      for (int rg = 0; rg < 4; ++rg)
        pa += sInv[rt * 16 + g * 4 + rg] * accP[rt][dt][rg];
    pa += __shfl_xor(pa, 16);
    pa += __shfl_xor(pa, 32);
    if (g == 0) sPool[w * 48 + dt * 16 + lam] = pa;   // unique writer per d
  }
  __syncthreads();
  if (t < DD) {
    float* ac = accum + ((size_t)side * BB + b) * 2 * DD;
    float ps = 0.f;
    const float* sp = selfb + t;
    #pragma unroll 4
    for (int r = 0; r < QB; ++r) ps = fmaf(sInv[r], sp[(size_t)r * DD], ps);
    atomicAdd(&ac[t], ps);
    atomicAdd(&ac[DD + t], sPool[t]);
  }
}

// ---------------- Finalize: divide by mask count, final l2norm ----------------
__global__ __launch_bounds__(256) void finalize_kernel(
    const float* __restrict__ accum, const int* __restrict__ qm,
    const int* __restrict__ am, float* __restrict__ out)
{
  const int b    = blockIdx.x & (BB - 1);
  const int side = blockIdx.x >> 7;
  const int* msk = side ? am : qm;
  const int t = threadIdx.x;
  __shared__ float red[8];

  float c = (float)msk[(size_t)b * LL + t];
  #pragma unroll
  for (int off = 1; off < 64; off <<= 1) c += __shfl_xor(c, off);
  if ((t & 63) == 0) red[t >> 6] = c;
  __syncthreads();
  float cnt = fmaxf(red[0] + red[1] + red[2] + red[3], 1e-9f);

  const float* ac = accum + ((size_t)side * BB + b) * 2 * DD;
  float v[3];
  float ssq = 0.f;
  #pragma unroll
  for (int i = 0; i < 3; ++i) {
    v[i] = ac[t * 3 + i] / cnt;
    ssq += v[i] * v[i];
  }
  #pragma unroll
  for (int off = 1; off < 64; off <<= 1) ssq += __shfl_xor(ssq, off);
  __syncthreads();
  if ((t & 63) == 0) red[t >> 6] = ssq;
  __syncthreads();
  float n = sqrtf(red[0] + red[1] + red[2] + red[3]);
  float inv = 1.f / fmaxf(n, 1e-12f);
  float* ob = out + ((size_t)side * BB + b) * 2 * DD;
  #pragma unroll
  for (int i = 0; i < 3; ++i) ob[t * 3 + i] = v[i] * inv;
}

extern "C" void kernel_launch(void* const* d_in, const int* in_sizes, int n_in,
                              void* d_out, int out_size, void* d_ws, size_t ws_size,
                              hipStream_t stream) {
  const float* qf = (const float*)d_in[0];
  const float* af = (const float*)d_in[1];
  const int*   qm = (const int*)d_in[2];
  const int*   am = (const int*)d_in[3];
  float* out   = (float*)d_out;
  float* accum = (float*)d_ws;   // 2*128*768*4 = 786 KB

  (void)hipMemsetAsync(accum, 0, sizeof(float) * 2 * BB * 2 * DD, stream);
  fused_kernel<<<dim3(1024), 512, 0, stream>>>(qf, af, qm, am, accum);
  finalize_kernel<<<256, 256, 0, stream>>>(accum, qm, am, out);
}